// Round 7
// baseline (1287.122 us; speedup 1.0000x reference)
//
#include <hip/hip_runtime.h>
#include <math.h>

#define H 51
#define LSEQ 999
#define BTOT 2048
#define E 16
#define NBLK (BTOT / E)     // 128 blocks

#define ROWS 256            // 64 units * 4 gates (unit-major rows: row = u*4+m)
#define K1 64               // layer1 K: k=0..50 h1, k=63 x, rest zero
#define K2 128              // layer2 K: k=0..50 h1 (k=63 x slot, W2 col = 0), k=64..114 h2

// ws float offsets
#define WS_W1 0
#define WS_W2 (WS_W1 + ROWS * K1)
#define WS_B1 (WS_W2 + ROWS * K2)
#define WS_B2 (WS_B1 + ROWS)
#define WS_WL (WS_B2 + ROWS)
#define WS_BL (WS_WL + 64)

// LDS frames: 1 frame = one 32-K B-fragment plane (64 lanes x 16B)
#define FRAME 1024
#define NFRAMES 16
#define PART_OFF (NFRAMES * FRAME)
#define LDS_BYTES (PART_OFF + 2 * 128 * 4)   // double-buffered partials

// frame ids (hi plane; lo plane = +1)
#define F_L1(b, s) (((b) * 2 + (s)) * 2)       // [h1; x] B-frags, double-buffered: 0..7
#define F_H2(b, s) (8 + ((b) * 2 + (s)) * 2)   // h2 B-frags, double-buffered: 8..15

typedef __attribute__((ext_vector_type(8))) short bf16x8;
typedef __attribute__((ext_vector_type(4))) float f32x4;

// ---------------- prep: padded cat-matrices, unit-major rows ----------------
__global__ void prep_kernel(const float* __restrict__ Wih1, const float* __restrict__ Whh1,
                            const float* __restrict__ bih1, const float* __restrict__ bhh1,
                            const float* __restrict__ Wih2, const float* __restrict__ Whh2,
                            const float* __restrict__ bih2, const float* __restrict__ bhh2,
                            const float* __restrict__ Wlin, const float* __restrict__ blin,
                            float* __restrict__ ws) {
    int tid = threadIdx.x + blockIdx.x * blockDim.x;
    int nthr = blockDim.x * gridDim.x;
    for (int idx = tid; idx < ROWS * K1; idx += nthr) {
        int R = idx / K1, k = idx % K1;
        int u = R >> 2, m = R & 3;
        float v = 0.0f;
        if (u < H) {
            if (k < H) v = Whh1[(m * H + u) * H + k];
            else if (k == 63) v = Wih1[m * H + u];   // Wih1 is [204][1]
        }
        ws[WS_W1 + idx] = v;
    }
    for (int idx = tid; idx < ROWS * K2; idx += nthr) {
        int R = idx / K2, k = idx % K2;
        int u = R >> 2, m = R & 3;
        float v = 0.0f;
        if (u < H) {
            if (k < H) v = Wih2[(m * H + u) * H + k];
            else if (k >= 64 && k < 64 + H) v = Whh2[(m * H + u) * H + (k - 64)];
        }
        ws[WS_W2 + idx] = v;
    }
    for (int R = tid; R < ROWS; R += nthr) {
        int u = R >> 2, m = R & 3;
        float v1 = 0.0f, v2 = 0.0f;
        if (u < H) {
            v1 = bih1[m * H + u] + bhh1[m * H + u];
            v2 = bih2[m * H + u] + bhh2[m * H + u];
        }
        ws[WS_B1 + R] = v1;
        ws[WS_B2 + R] = v2;
    }
    for (int u = tid; u < 64; u += nthr) ws[WS_WL + u] = (u < H) ? Wlin[u] : 0.0f;
    if (tid == 0) ws[WS_BL] = blin[0];
}

// ---------------- helpers ----------------
__device__ __forceinline__ short f2bf(float f) {      // round-to-nearest-even
    unsigned u = __float_as_uint(f);
    unsigned r = (u + 0x7fffu + ((u >> 16) & 1u)) >> 16;
    return (short)r;
}
__device__ __forceinline__ float bf2f(short b) {
    return __uint_as_float(((unsigned)(unsigned short)b) << 16);
}
__device__ __forceinline__ float sigm(float x) {
    return __builtin_amdgcn_rcpf(1.0f + __expf(-x));
}
__device__ __forceinline__ float tanh_(float x) {
    return fmaf(-2.0f, __builtin_amdgcn_rcpf(__expf(2.0f * x) + 1.0f), 1.0f);
}
// scatter one h value into B-fragment layout: elems 0..3 <-> k=4g+j, 4..7 <-> 16+4g+j
__device__ __forceinline__ void wr_h(char* base, int fhi, int k, int e, short hi, short lo) {
    const int kk = k & 31;
    const int gg = (kk & 15) >> 2;
    const int j  = (kk & 3) + ((kk >> 4) << 2);
    const int off = (gg * 16 + e) * 16 + j * 2;
    *(short*)(base + (size_t)fhi * FRAME + off) = hi;
    *(short*)(base + (size_t)(fhi + 1) * FRAME + off) = lo;
}
__device__ __forceinline__ bf16x8 ld_fr(const char* base, int f, int l) {
    return *(const bf16x8*)(base + (size_t)f * FRAME + (size_t)l * 16);
}

// ---------------- main LSTM kernel (1 barrier per phase; L2 skewed by 1 step) ----------------
__global__ void __launch_bounds__(512, 1)
lstm_kernel(const float* __restrict__ x, const float* __restrict__ ws,
            float* __restrict__ out) {
    __shared__ __align__(16) char smem[LDS_BYTES];

    const int tid = threadIdx.x;
    const int w = tid >> 6;        // 0..7; each wave owns 2 row-tiles T = w*2+i
    const int l = tid & 63;
    const int g = l >> 4;
    const int e = l & 15;

    for (int i = tid; i < LDS_BYTES / 4; i += 512) ((float*)smem)[i] = 0.0f;

    // ---- prologue: register-resident W fragments (hi/lo bf16 split) ----
    bf16x8 w1h[2][2], w1l[2][2], w2h[2][4], w2l[2][4];
    f32x4 b1v[2], b2v[2];
    float wlr[2];
#pragma unroll
    for (int i = 0; i < 2; ++i) {
        const int T = w * 2 + i;
        const int rowA = T * 16 + e;
#pragma unroll
        for (int s = 0; s < 2; ++s) {
            bf16x8 hh, ll;
#pragma unroll
            for (int j = 0; j < 8; ++j) {
                const int k = s * 32 + ((j < 4) ? (4 * g + j) : (16 + 4 * g + (j - 4)));
                float wv = ws[WS_W1 + rowA * K1 + k];
                short hb = f2bf(wv);
                hh[j] = hb;
                ll[j] = f2bf(wv - bf2f(hb));
            }
            w1h[i][s] = hh; w1l[i][s] = ll;
        }
#pragma unroll
        for (int s = 0; s < 4; ++s) {
            bf16x8 hh, ll;
#pragma unroll
            for (int j = 0; j < 8; ++j) {
                const int k = s * 32 + ((j < 4) ? (4 * g + j) : (16 + 4 * g + (j - 4)));
                float wv = ws[WS_W2 + rowA * K2 + k];
                short hb = f2bf(wv);
                hh[j] = hb;
                ll[j] = f2bf(wv - bf2f(hb));
            }
            w2h[i][s] = hh; w2l[i][s] = ll;
        }
#pragma unroll
        for (int r = 0; r < 4; ++r) {
            b1v[i][r] = ws[WS_B1 + T * 16 + 4 * g + r];
            b2v[i][r] = ws[WS_B2 + T * 16 + 4 * g + r];
        }
        wlr[i] = ws[WS_WL + T * 4 + g];
    }
    const float blv = ws[WS_BL];

    const int b0 = blockIdx.x * E;
    const float* xp = x + (size_t)(b0 + e) * LSEQ;   // used by wave0 lanes<16 only
    float* pparts = (float*)(smem + PART_OFF);

    __syncthreads();   // zero-init complete

    float xv = 0.0f;
    if (w == 0 && l < 16) {
        float x0 = xp[0];
        short hb = f2bf(x0);
        wr_h(smem, F_L1(0, 1), 63, e, hb, f2bf(x0 - bf2f(hb)));   // x(0) -> buf0 k=63
        xv = xp[1];                                               // x(1), written at phase 0
    }

    float c1s[2] = {0.f, 0.f};
    float c2s[2] = {0.f, 0.f};

    __syncthreads();   // x(0) visible

    // Phase t: L1 computes h1(t) from a1 = [h1(t-1); x(t)] (buf q=t&1);
    //          L2 computes h2(t-1), out-partials(t-1) from same a1 + h2(t-2) (F_H2 buf q).
    // One barrier per phase.
    for (int t = 0; t <= LSEQ; ++t) {
        const int q = t & 1;

        // ---- phase-start loads ----
        bf16x8 a1h[2], a1l[2], h2h[2], h2l[2];
#pragma unroll
        for (int s = 0; s < 2; ++s) {
            a1h[s] = ld_fr(smem, F_L1(q, s), l);
            a1l[s] = ld_fr(smem, F_L1(q, s) + 1, l);
            h2h[s] = ld_fr(smem, F_H2(q, s), l);
            h2l[s] = ld_fr(smem, F_H2(q, s) + 1, l);
        }

        // out(t-2): gather partials written at phase t-1 (buffer q^1)
        if (w == 1 && l < 16 && t >= 2) {
            const float* pp = pparts + (q ^ 1) * 128;
            float r = ((pp[l] + pp[16 + l]) + (pp[32 + l] + pp[48 + l])) +
                      ((pp[64 + l] + pp[80 + l]) + (pp[96 + l] + pp[112 + l]));
            out[(size_t)(b0 + l) * LSEQ + (t - 2)] = r + blv;
        }

        // write x(t+1) into next a1 buf; prefetch x(t+2)
        float xnew = 0.0f;
        if (w == 0 && l < 16) {
            xnew = xp[(t + 2 < LSEQ) ? (t + 2) : (LSEQ - 1)];
            short hb = f2bf(xv);
            wr_h(smem, F_L1(q ^ 1, 1), 63, e, hb, f2bf(xv - bf2f(hb)));
        }

        // ---- MFMAs: 6 independent chains per lane (acc1, acc2a, acc2b x 2 tiles) ----
        f32x4 acc1[2], acc2a[2], acc2b[2];
#pragma unroll
        for (int i = 0; i < 2; ++i) {
            acc1[i] = b1v[i];
            acc2a[i] = b2v[i];
            acc2b[i] = (f32x4){0.f, 0.f, 0.f, 0.f};
        }
#pragma unroll
        for (int s = 0; s < 2; ++s)
#pragma unroll
            for (int i = 0; i < 2; ++i) {
                acc1[i]  = __builtin_amdgcn_mfma_f32_16x16x32_bf16(w1h[i][s],     a1h[s], acc1[i],  0, 0, 0);
                acc2a[i] = __builtin_amdgcn_mfma_f32_16x16x32_bf16(w2h[i][s],     a1h[s], acc2a[i], 0, 0, 0);
                acc2b[i] = __builtin_amdgcn_mfma_f32_16x16x32_bf16(w2h[i][s + 2], h2h[s], acc2b[i], 0, 0, 0);
                acc1[i]  = __builtin_amdgcn_mfma_f32_16x16x32_bf16(w1h[i][s],     a1l[s], acc1[i],  0, 0, 0);
                acc2a[i] = __builtin_amdgcn_mfma_f32_16x16x32_bf16(w2h[i][s],     a1l[s], acc2a[i], 0, 0, 0);
                acc2b[i] = __builtin_amdgcn_mfma_f32_16x16x32_bf16(w2h[i][s + 2], h2l[s], acc2b[i], 0, 0, 0);
                acc1[i]  = __builtin_amdgcn_mfma_f32_16x16x32_bf16(w1l[i][s],     a1h[s], acc1[i],  0, 0, 0);
                acc2a[i] = __builtin_amdgcn_mfma_f32_16x16x32_bf16(w2l[i][s],     a1h[s], acc2a[i], 0, 0, 0);
                acc2b[i] = __builtin_amdgcn_mfma_f32_16x16x32_bf16(w2l[i][s + 2], h2h[s], acc2b[i], 0, 0, 0);
            }

        // ---- L1 activations -> h1(t) scatter into F_L1(q^1) ----
#pragma unroll
        for (int i = 0; i < 2; ++i) {
            float ig = sigm(acc1[i][0]), fg = sigm(acc1[i][1]);
            float gg = tanh_(acc1[i][2]), og = sigm(acc1[i][3]);
            c1s[i] = fg * c1s[i] + ig * gg;
            float h1 = og * tanh_(c1s[i]);
            short hb = f2bf(h1);
            short lb = f2bf(h1 - bf2f(hb));
            const int u = (w * 2 + i) * 4 + g;
            if (u < 63) wr_h(smem, F_L1(q ^ 1, u >> 5), u, e, hb, lb);  // k=63 is x's slot
        }

        // ---- L2 activations (step t-1) -> h2 scatter + output partial ----
        if (t > 0) {
            float pr = 0.0f;
#pragma unroll
            for (int i = 0; i < 2; ++i) {
                f32x4 a2 = acc2a[i] + acc2b[i];
                float ig = sigm(a2[0]), fg = sigm(a2[1]);
                float gg = tanh_(a2[2]), og = sigm(a2[3]);
                c2s[i] = fg * c2s[i] + ig * gg;
                float h2 = og * tanh_(c2s[i]);
                short hb = f2bf(h2);
                short lb = f2bf(h2 - bf2f(hb));
                const int u = (w * 2 + i) * 4 + g;
                wr_h(smem, F_H2(q ^ 1, u >> 5), 64 + u, e, hb, lb);
                pr = fmaf(wlr[i], h2, pr);
            }
            pr += __shfl_xor(pr, 16);
            pr += __shfl_xor(pr, 32);
            if (l < 16) pparts[q * 128 + w * 16 + l] = pr;
        }

        __syncthreads();
        xv = xnew;
    }

    // final output: out(LSEQ-1) from partials written at phase LSEQ (buffer LSEQ&1)
    if (w == 1 && l < 16) {
        const float* pp = pparts + (LSEQ & 1) * 128;
        float r = ((pp[l] + pp[16 + l]) + (pp[32 + l] + pp[48 + l])) +
                  ((pp[64 + l] + pp[80 + l]) + (pp[96 + l] + pp[112 + l]));
        out[(size_t)(b0 + l) * LSEQ + (LSEQ - 1)] = r + blv;
    }
}

extern "C" void kernel_launch(void* const* d_in, const int* in_sizes, int n_in,
                              void* d_out, int out_size, void* d_ws, size_t ws_size,
                              hipStream_t stream) {
    const float* x    = (const float*)d_in[0];
    const float* Wih1 = (const float*)d_in[1];
    const float* Whh1 = (const float*)d_in[2];
    const float* bih1 = (const float*)d_in[3];
    const float* bhh1 = (const float*)d_in[4];
    const float* Wih2 = (const float*)d_in[5];
    const float* Whh2 = (const float*)d_in[6];
    const float* bih2 = (const float*)d_in[7];
    const float* bhh2 = (const float*)d_in[8];
    const float* Wlin = (const float*)d_in[9];
    const float* blin = (const float*)d_in[10];
    float* ws  = (float*)d_ws;
    float* out = (float*)d_out;

    hipLaunchKernelGGL(prep_kernel, dim3(64), dim3(256), 0, stream,
                       Wih1, Whh1, bih1, bhh1, Wih2, Whh2, bih2, bhh2, Wlin, blin, ws);
    hipLaunchKernelGGL(lstm_kernel, dim3(NBLK), dim3(512), 0, stream, x, ws, out);
}